// Round 1
// baseline (302.419 us; speedup 1.0000x reference)
//
#include <hip/hip_runtime.h>

// SSIM fused kernel: 5 "convolutions" collapsed into one 3x3 stencil pass.
// x,y: [64,1,480,640] f32. Output: scalar f32 = 1 - mean(ssim).

#define IMG_H 480
#define IMG_W 640
#define IMG_B 64
#define NPIX (IMG_B * IMG_H * IMG_W)   // 19,660,800
#define NBLOCKS 2048
#define NTHREADS 256

__device__ __forceinline__ float block_reduce_sum(float v) {
    // wave64 shuffle reduce
    for (int off = 32; off > 0; off >>= 1)
        v += __shfl_down(v, off, 64);
    __shared__ float s[NTHREADS / 64];
    const int lane = threadIdx.x & 63;
    const int wid  = threadIdx.x >> 6;
    if (lane == 0) s[wid] = v;
    __syncthreads();
    float t = 0.0f;
    if (threadIdx.x == 0) {
#pragma unroll
        for (int i = 0; i < NTHREADS / 64; ++i) t += s[i];
    }
    return t;  // valid only on thread 0
}

__global__ void ssim_partial_kernel(const float* __restrict__ x,
                                    const float* __restrict__ y,
                                    float* __restrict__ partials) {
    // 3x3 Gaussian window (outer product of g with itself), f32, matches ref
    const float g0 = 0.0113f, g1 = 0.0838f;
    const float wgt[3] = {g0, g1, g0};
    const float C1 = 1e-4f;   // 0.01^2
    const float C2 = 9e-4f;   // 0.03^2

    float local = 0.0f;
    const int stride = gridDim.x * blockDim.x;
    for (int idx = blockIdx.x * blockDim.x + threadIdx.x; idx < NPIX; idx += stride) {
        const int b  = idx / (IMG_H * IMG_W);
        const int r  = idx - b * (IMG_H * IMG_W);
        const int h  = r / IMG_W;
        const int w  = r - h * IMG_W;
        const int base = b * (IMG_H * IMG_W);

        float mu_x = 0.0f, mu_y = 0.0f, sxx = 0.0f, syy = 0.0f, sxy = 0.0f;
#pragma unroll
        for (int dy = -1; dy <= 1; ++dy) {
            const int hh = h + dy;
            if (hh < 0 || hh >= IMG_H) continue;
            const float wy = wgt[dy + 1];
            const int rowbase = base + hh * IMG_W;
#pragma unroll
            for (int dx = -1; dx <= 1; ++dx) {
                const int ww = w + dx;
                if (ww < 0 || ww >= IMG_W) continue;
                const float wv = wy * wgt[dx + 1];
                const float xv = x[rowbase + ww];
                const float yv = y[rowbase + ww];
                const float wx = wv * xv;
                const float wyv = wv * yv;
                mu_x += wx;
                mu_y += wyv;
                sxx  += wx * xv;
                syy  += wyv * yv;
                sxy  += wx * yv;
            }
        }

        const float sigma_x  = sxx - mu_x * mu_x;
        const float sigma_y  = syy - mu_y * mu_y;
        const float sigma_xy = sxy - mu_x * mu_y;

        const float num = (2.0f * mu_x * mu_y + C1) * (2.0f * sigma_xy + C2);
        const float den = (mu_x * mu_x + mu_y * mu_y + C1) * (sigma_x + sigma_y + C2);
        local += num / den;
    }

    const float bsum = block_reduce_sum(local);
    if (threadIdx.x == 0) partials[blockIdx.x] = bsum;
}

__global__ void ssim_finalize_kernel(const float* __restrict__ partials,
                                     float* __restrict__ out) {
    // 2048 partials reduced by one block of 256 threads, double accumulate
    double acc = 0.0;
    for (int i = threadIdx.x; i < NBLOCKS; i += NTHREADS)
        acc += (double)partials[i];
    // reduce doubles via float path is lossy; do LDS double reduce
    __shared__ double s[NTHREADS];
    s[threadIdx.x] = acc;
    __syncthreads();
    for (int off = NTHREADS / 2; off > 0; off >>= 1) {
        if (threadIdx.x < off) s[threadIdx.x] += s[threadIdx.x + off];
        __syncthreads();
    }
    if (threadIdx.x == 0) {
        const double mean = s[0] / (double)NPIX;
        out[0] = (float)(1.0 - mean);
    }
}

extern "C" void kernel_launch(void* const* d_in, const int* in_sizes, int n_in,
                              void* d_out, int out_size, void* d_ws, size_t ws_size,
                              hipStream_t stream) {
    const float* x = (const float*)d_in[0];
    const float* y = (const float*)d_in[1];
    float* partials = (float*)d_ws;
    float* out = (float*)d_out;

    ssim_partial_kernel<<<NBLOCKS, NTHREADS, 0, stream>>>(x, y, partials);
    ssim_finalize_kernel<<<1, NTHREADS, 0, stream>>>(partials, out);
}

// Round 2
// 192.638 us; speedup vs baseline: 1.5699x; 1.5699x over previous
//
#include <hip/hip_runtime.h>

// SSIM fused: separable 3x3 Gaussian, 5 maps computed in one pass.
// Each thread: 4 consecutive pixels wide, walks down a ROWS-row strip,
// keeping 3 horizontally-filtered rows of all 5 maps in registers.

#define IMG_H 480
#define IMG_W 640
#define IMG_B 64
#define NPIX (IMG_B * IMG_H * IMG_W)   // 19,660,800
#define ROWS 20
#define STRIPS (IMG_H / ROWS)          // 24
#define QCOLS (IMG_W / 4)              // 160
#define NTH 256
#define NITEMS (IMG_B * STRIPS * QCOLS) // 245,760
#define NBLK (NITEMS / NTH)             // 960

__device__ __forceinline__ void hfilt_row(const float* __restrict__ xr,
                                          const float* __restrict__ yr,
                                          int c,
                                          float4& mx, float4& my,
                                          float4& sxx, float4& syy, float4& sxy) {
    const float g0 = 0.0113f, g1 = 0.0838f;
    const float4 x4 = *(const float4*)(xr + 4 * c);
    const float4 y4 = *(const float4*)(yr + 4 * c);
    const float xl = (c > 0)         ? xr[4 * c - 1] : 0.0f;
    const float xg = (c < QCOLS - 1) ? xr[4 * c + 4] : 0.0f;
    const float yl = (c > 0)         ? yr[4 * c - 1] : 0.0f;
    const float yg = (c < QCOLS - 1) ? yr[4 * c + 4] : 0.0f;

    const float xs[6] = {xl, x4.x, x4.y, x4.z, x4.w, xg};
    const float ys[6] = {yl, y4.x, y4.y, y4.z, y4.w, yg};
    float xx[6], yy[6], xy[6];
#pragma unroll
    for (int j = 0; j < 6; ++j) {
        xx[j] = xs[j] * xs[j];
        yy[j] = ys[j] * ys[j];
        xy[j] = xs[j] * ys[j];
    }
    float o[5][4];
#pragma unroll
    for (int j = 0; j < 4; ++j) {
        o[0][j] = g0 * (xs[j] + xs[j + 2]) + g1 * xs[j + 1];
        o[1][j] = g0 * (ys[j] + ys[j + 2]) + g1 * ys[j + 1];
        o[2][j] = g0 * (xx[j] + xx[j + 2]) + g1 * xx[j + 1];
        o[3][j] = g0 * (yy[j] + yy[j + 2]) + g1 * yy[j + 1];
        o[4][j] = g0 * (xy[j] + xy[j + 2]) + g1 * xy[j + 1];
    }
    mx  = make_float4(o[0][0], o[0][1], o[0][2], o[0][3]);
    my  = make_float4(o[1][0], o[1][1], o[1][2], o[1][3]);
    sxx = make_float4(o[2][0], o[2][1], o[2][2], o[2][3]);
    syy = make_float4(o[3][0], o[3][1], o[3][2], o[3][3]);
    sxy = make_float4(o[4][0], o[4][1], o[4][2], o[4][3]);
}

__device__ __forceinline__ float4 zero4() { return make_float4(0.f, 0.f, 0.f, 0.f); }

__global__ __launch_bounds__(NTH) void ssim_partial_kernel(
        const float* __restrict__ x, const float* __restrict__ y,
        float* __restrict__ partials) {
    const float g0 = 0.0113f, g1 = 0.0838f;
    const float C1 = 1e-4f, C2 = 9e-4f;

    const int tid = blockIdx.x * NTH + threadIdx.x;
    const int c = tid % QCOLS;
    const int t = tid / QCOLS;
    const int s = t % STRIPS;
    const int b = t / STRIPS;

    const float* xb = x + (size_t)b * IMG_H * IMG_W;
    const float* yb = y + (size_t)b * IMG_H * IMG_W;
    const int h0 = s * ROWS;

    // 3 rows of 5 horizontally-filtered maps: prev / cur / next
    float4 pmx, pmy, psxx, psyy, psxy;
    float4 cmx, cmy, csxx, csyy, csxy;
    float4 nmx, nmy, nsxx, nsyy, nsxy;

    if (h0 > 0) {
        hfilt_row(xb + (size_t)(h0 - 1) * IMG_W, yb + (size_t)(h0 - 1) * IMG_W, c,
                  pmx, pmy, psxx, psyy, psxy);
    } else {
        pmx = pmy = psxx = psyy = psxy = zero4();
    }
    hfilt_row(xb + (size_t)h0 * IMG_W, yb + (size_t)h0 * IMG_W, c,
              cmx, cmy, csxx, csyy, csxy);

    float local = 0.0f;
#pragma unroll 4
    for (int h = h0; h < h0 + ROWS; ++h) {
        const int hn = h + 1;
        if (hn < IMG_H) {
            hfilt_row(xb + (size_t)hn * IMG_W, yb + (size_t)hn * IMG_W, c,
                      nmx, nmy, nsxx, nsyy, nsxy);
        } else {
            nmx = nmy = nsxx = nsyy = nsxy = zero4();
        }

        // vertical combine + SSIM for 4 pixels
        const float vmx[4]  = {g0 * (pmx.x + nmx.x) + g1 * cmx.x,
                               g0 * (pmx.y + nmx.y) + g1 * cmx.y,
                               g0 * (pmx.z + nmx.z) + g1 * cmx.z,
                               g0 * (pmx.w + nmx.w) + g1 * cmx.w};
        const float vmy[4]  = {g0 * (pmy.x + nmy.x) + g1 * cmy.x,
                               g0 * (pmy.y + nmy.y) + g1 * cmy.y,
                               g0 * (pmy.z + nmy.z) + g1 * cmy.z,
                               g0 * (pmy.w + nmy.w) + g1 * cmy.w};
        const float vxx[4]  = {g0 * (psxx.x + nsxx.x) + g1 * csxx.x,
                               g0 * (psxx.y + nsxx.y) + g1 * csxx.y,
                               g0 * (psxx.z + nsxx.z) + g1 * csxx.z,
                               g0 * (psxx.w + nsxx.w) + g1 * csxx.w};
        const float vyy[4]  = {g0 * (psyy.x + nsyy.x) + g1 * csyy.x,
                               g0 * (psyy.y + nsyy.y) + g1 * csyy.y,
                               g0 * (psyy.z + nsyy.z) + g1 * csyy.z,
                               g0 * (psyy.w + nsyy.w) + g1 * csyy.w};
        const float vxy[4]  = {g0 * (psxy.x + nsxy.x) + g1 * csxy.x,
                               g0 * (psxy.y + nsxy.y) + g1 * csxy.y,
                               g0 * (psxy.z + nsxy.z) + g1 * csxy.z,
                               g0 * (psxy.w + nsxy.w) + g1 * csxy.w};

#pragma unroll
        for (int j = 0; j < 4; ++j) {
            const float mu_x = vmx[j], mu_y = vmy[j];
            const float sigma_x  = vxx[j] - mu_x * mu_x;
            const float sigma_y  = vyy[j] - mu_y * mu_y;
            const float sigma_xy = vxy[j] - mu_x * mu_y;
            const float num = (2.0f * mu_x * mu_y + C1) * (2.0f * sigma_xy + C2);
            const float den = (mu_x * mu_x + mu_y * mu_y + C1) *
                              (sigma_x + sigma_y + C2);
            local += num * __builtin_amdgcn_rcpf(den);
        }

        // shift ring
        pmx = cmx; pmy = cmy; psxx = csxx; psyy = csyy; psxy = csxy;
        cmx = nmx; cmy = nmy; csxx = nsxx; csyy = nsyy; csxy = nsxy;
    }

    // block reduce
    for (int off = 32; off > 0; off >>= 1)
        local += __shfl_down(local, off, 64);
    __shared__ float sred[NTH / 64];
    const int lane = threadIdx.x & 63;
    const int wid  = threadIdx.x >> 6;
    if (lane == 0) sred[wid] = local;
    __syncthreads();
    if (threadIdx.x == 0) {
        float t0 = 0.0f;
#pragma unroll
        for (int i = 0; i < NTH / 64; ++i) t0 += sred[i];
        partials[blockIdx.x] = t0;
    }
}

__global__ void ssim_finalize_kernel(const float* __restrict__ partials,
                                     float* __restrict__ out) {
    double acc = 0.0;
    for (int i = threadIdx.x; i < NBLK; i += NTH)
        acc += (double)partials[i];
    __shared__ double s[NTH];
    s[threadIdx.x] = acc;
    __syncthreads();
    for (int off = NTH / 2; off > 0; off >>= 1) {
        if (threadIdx.x < off) s[threadIdx.x] += s[threadIdx.x + off];
        __syncthreads();
    }
    if (threadIdx.x == 0) {
        const double mean = s[0] / (double)NPIX;
        out[0] = (float)(1.0 - mean);
    }
}

extern "C" void kernel_launch(void* const* d_in, const int* in_sizes, int n_in,
                              void* d_out, int out_size, void* d_ws, size_t ws_size,
                              hipStream_t stream) {
    const float* x = (const float*)d_in[0];
    const float* y = (const float*)d_in[1];
    float* partials = (float*)d_ws;
    float* out = (float*)d_out;

    ssim_partial_kernel<<<NBLK, NTH, 0, stream>>>(x, y, partials);
    ssim_finalize_kernel<<<1, NTH, 0, stream>>>(partials, out);
}